// Round 17
// baseline (694.612 us; speedup 1.0000x reference)
//
#include <hip/hip_runtime.h>
#include <math.h>

typedef short s16x8 __attribute__((ext_vector_type(8)));
typedef float f32x4 __attribute__((ext_vector_type(4)));
typedef unsigned short u16;

// ---------------- problem constants ----------------
#define B_    32
#define CIN   128
#define CHID  256
#define H_    60
#define W_    80
#define COUT  65
#define HP    480
#define WP    640
#define TOPK  1000
#define CAND_MAX 8192
#define DET_THRESH 0.015f

// ---------------- output layout (floats) ----------------
#define LOGITS_N (B_*COUT*H_*W_)
#define PROB_N   (B_*HP*WP)
#define PROB_OFF (LOGITS_N)
#define NMS_OFF  (PROB_OFF + PROB_N)
#define PRED_OFF (NMS_OFF + PROB_N)

// ---------------- workspace layout (float offsets) ----------------
#define WB_FN    442368
#define SA_OFF   WB_FN
#define TA_OFF   (SA_OFF + 256)
#define TB_OFF   (TA_OFF + 256)
#define WB1_FN   30720
#define WB1_OFF  (TB_OFF + 128)
#define H_OFF    (WB1_OFF + WB1_FN)
#define H_N      (B_*H_*W_*CHID)
#define CAND_OFF (H_OFF + H_N)
#define CNT_OFF  (CAND_OFF + B_*CAND_MAX)
#define CNT_N    (32*32)
#define KTH_OFF  (CNT_OFF + CNT_N)
#define WT_N     (CHID*CIN*9)
#define WB1_U16N 61440

// conv3 LDS A-layout: unit (pos,kg) at dword 29*pos + 8*kg.
#define AROW  58
#define APLN  6264

// bf16 helpers (RNE)
__device__ __forceinline__ u16 f2bf(float x) {
    unsigned u = __float_as_uint(x);
    return (u16)((u + 0x7fffu + ((u >> 16) & 1u)) >> 16);
}
__device__ __forceinline__ float bf2f(u16 h) {
    return __uint_as_float(((unsigned)h) << 16);
}

#define MFMA16 __builtin_amdgcn_mfma_f32_16x16x32_bf16

// =====================================================================
// K0: prep — WB (conv3 3-plane split), WB1 (conv1 3-plane split, padded
// to 80 oc, per-fragment layout), sa/ta conv3 BN, tb conv1 BN bias.
// =====================================================================
__global__ void prep_kernel(const float* __restrict__ wa,
                            const float* __restrict__ ba, const float* __restrict__ ga,
                            const float* __restrict__ bta, const float* __restrict__ ma,
                            const float* __restrict__ va,
                            const float* __restrict__ wb, const float* __restrict__ bb,
                            const float* __restrict__ gb, const float* __restrict__ btb,
                            const float* __restrict__ mb, const float* __restrict__ vb,
                            u16* __restrict__ WBo,
                            float* __restrict__ sa, float* __restrict__ ta,
                            float* __restrict__ tb, u16* __restrict__ WB1o)
{
    int gid = blockIdx.x * 256 + threadIdx.x;
    if (gid < WT_N) {
        int icl = gid & 31;
        int ocl = (gid >> 5) & 63;
        int rest = gid >> 11;          // [0,144)
        int tap = rest % 9;
        int cq = rest / 9;             // [0,16)
        int icc = cq & 3, ocq = cq >> 2;
        float v = wa[(((ocq * 64 + ocl) * CIN) + icc * 32 + icl) * 9 + tap];
        u16 hh = f2bf(v); float r1 = v - bf2f(hh);
        u16 mm2 = f2bf(r1); float r2 = r1 - bf2f(mm2);
        u16 ll = f2bf(r2);
        size_t base = ((size_t)(((ocq * 4 + icc) * 9 + tap) * 3)) * 2048
                      + ocl * 32 + icl;
        WBo[base] = hh;
        WBo[base + 2048] = mm2;
        WBo[base + 4096] = ll;
    } else if (gid < WT_N + 256) {
        int oc = gid - WT_N;
        float inv = ga[oc] / sqrtf(va[oc] + 1e-5f);
        sa[oc] = inv;
        ta[oc] = (ba[oc] - ma[oc]) * inv + bta[oc];
    } else if (gid < WT_N + 256 + COUT) {
        int oc = gid - (WT_N + 256);
        float inv = gb[oc] / sqrtf(vb[oc] + 1e-5f);
        tb[oc] = (bb[oc] - mb[oc]) * inv + btb[oc];
    } else if (gid < WT_N + 256 + COUT + WB1_U16N) {
        int idx = gid - (WT_N + 256 + COUT);
        int within = idx & 511;
        int j = within & 7;
        int lane = within >> 3;
        int chunk = idx >> 9;          // [0,120)
        int plane = chunk % 3;
        int kc = (chunk / 3) & 7;
        int ocf = chunk / 24;
        int oc = ocf * 16 + (lane & 15);
        int k = kc * 32 + (lane >> 4) * 8 + j;
        float v = 0.f;
        if (oc < COUT) {
            float inv = gb[oc] / sqrtf(vb[oc] + 1e-5f);
            v = wb[oc * CHID + k] * inv;
        }
        u16 hh = f2bf(v); float r1 = v - bf2f(hh);
        u16 mm2 = f2bf(r1); float r2 = r1 - bf2f(mm2);
        u16 ll = f2bf(r2);
        WB1o[idx] = (plane == 0) ? hh : (plane == 1) ? mm2 : ll;
    }
}

// =====================================================================
// K1: conv3x3 via 6-term split-bf16 MFMA.
// Round-17: DOUBLE-BUFFERED xsA (75.2 KB) — per icc: issue icc+1 loads,
// compute taps 0-3, convert+write icc+1 into the other buffer (hidden
// under MFMAs), compute taps 4-8, ONE barrier. Write phase off the
// critical path; barriers halved. MFMA order bit-identical to r14/r16.
// =====================================================================
__global__ __launch_bounds__(256, 2) void conv3_kernel(const float* __restrict__ x,
                                                       const u16* __restrict__ WB,
                                                       const float* __restrict__ sa,
                                                       const float* __restrict__ ta,
                                                       float* __restrict__ h)
{
    __shared__ __align__(16) u16 xsA[2][3 * APLN];   // 75168 B

    // bijective XCD swizzle: 2400 blocks = 8 * 300
    int d = blockIdx.x;
    int o = (d & 7) * 300 + (d >> 3);
    int tile = o % 75;
    int b = o / 75;
    int ty = tile / 5, tx = tile % 5;
    int y0 = ty * 4, x0 = tx * 16;

    int t = threadIdx.x;
    int wv = __builtin_amdgcn_readfirstlane(t >> 6);   // 0..3 = ocq
    int lane = t & 63;
    int cx = lane & 15;
    int kg = lane >> 4;
    int icl0 = kg * 8;

    const float* xb = x + (size_t)b * CIN * H_ * W_;

    // staging offsets, computed once
    int goff[14];
#pragma unroll
    for (int j = 0; j < 14; ++j) {
        int e = t + j * 256;
        int go = -1;
        if (e < 3456) {
            int xx = e % 18;
            int yy = (e / 18) % 6;
            int icl = e / 108;
            int gy = y0 + yy - 1, gx = x0 + xx - 1;
            if (gy >= 0 && gy < H_ && gx >= 0 && gx < W_)
                go = icl * (H_ * W_) + gy * W_ + gx;
        }
        goff[j] = go;
    }

    f32x4 acc[4][4];
#pragma unroll
    for (int pb = 0; pb < 4; ++pb)
#pragma unroll
        for (int f = 0; f < 4; ++f) acc[pb][f] = (f32x4)(0.f);

    // prologue: load icc=0 slab, convert+write into buf 0
    float xr[14];
#pragma unroll
    for (int j = 0; j < 14; ++j)
        xr[j] = (goff[j] >= 0) ? xb[goff[j]] : 0.f;
#pragma unroll
    for (int j = 0; j < 14; ++j) {
        int e = t + j * 256;
        if (e < 3456) {
            int xx = e % 18;
            int yy = (e / 18) % 6;
            int icl = e / 108;
            float v = xr[j];
            u16 hh = f2bf(v); float r1 = v - bf2f(hh);
            u16 mm2 = f2bf(r1); float r2 = r1 - bf2f(mm2);
            u16 ll = f2bf(r2);
            int pos = yy * 18 + xx;
            int wu = pos * AROW + ((icl >> 3) << 4) + (icl & 7);
            xsA[0][wu] = hh;
            xsA[0][APLN + wu] = mm2;
            xsA[0][2 * APLN + wu] = ll;
        }
    }
    __syncthreads();

#pragma unroll 1
    for (int icc = 0; icc < 4; ++icc) {
        int cur = icc & 1;
        const u16* xa = xsA[cur];

        // issue-early: icc+1's global loads (land during taps 0-3)
        if (icc < 3) {
            const float* xc = xb + (icc + 1) * 32 * (H_ * W_);
#pragma unroll
            for (int j = 0; j < 14; ++j)
                if (goff[j] >= 0) xr[j] = xc[goff[j]];
        }

        // taps 0..3
#pragma unroll 1
        for (int tap = 0; tap < 4; ++tap) {
            int dy = tap / 3, dx = tap - dy * 3;
            const u16* bb_ = WB + ((size_t)(((wv * 4 + icc) * 9 + tap) * 3)) * 2048;
            s16x8 Bh[4], Bm[4], Bl[4];
#pragma unroll
            for (int f = 0; f < 4; ++f) {
                int bu = (f * 16 + cx) * 32 + icl0;
                Bh[f] = *(const s16x8*)&bb_[bu];
                Bm[f] = *(const s16x8*)&bb_[2048 + bu];
                Bl[f] = *(const s16x8*)&bb_[4096 + bu];
            }
#pragma unroll
            for (int pb = 0; pb < 4; ++pb) {
                int pos = (pb + dy) * 18 + cx + dx;
                int au = pos * AROW + (kg << 4);
                s16x8 Ah = *(const s16x8*)&xa[au];
                s16x8 Am = *(const s16x8*)&xa[APLN + au];
                s16x8 Al = *(const s16x8*)&xa[2 * APLN + au];
#pragma unroll
                for (int f = 0; f < 4; ++f) {
                    acc[pb][f] = MFMA16(Ah, Bh[f], acc[pb][f], 0, 0, 0);
                    acc[pb][f] = MFMA16(Ah, Bm[f], acc[pb][f], 0, 0, 0);
                    acc[pb][f] = MFMA16(Am, Bh[f], acc[pb][f], 0, 0, 0);
                    acc[pb][f] = MFMA16(Ah, Bl[f], acc[pb][f], 0, 0, 0);
                    acc[pb][f] = MFMA16(Am, Bm[f], acc[pb][f], 0, 0, 0);
                    acc[pb][f] = MFMA16(Al, Bh[f], acc[pb][f], 0, 0, 0);
                }
            }
        }

        // write-mid: convert + store icc+1 into the OTHER buffer
        // (no barrier needed: reads target buf[cur], writes buf[cur^1])
        if (icc < 3) {
            u16* xw = xsA[cur ^ 1];
#pragma unroll
            for (int j = 0; j < 14; ++j) {
                int e = t + j * 256;
                if (e < 3456) {
                    int xx = e % 18;
                    int yy = (e / 18) % 6;
                    int icl = e / 108;
                    float v = xr[j];
                    u16 hh = f2bf(v); float r1 = v - bf2f(hh);
                    u16 mm2 = f2bf(r1); float r2 = r1 - bf2f(mm2);
                    u16 ll = f2bf(r2);
                    int pos = yy * 18 + xx;
                    int wu = pos * AROW + ((icl >> 3) << 4) + (icl & 7);
                    xw[wu] = hh;
                    xw[APLN + wu] = mm2;
                    xw[2 * APLN + wu] = ll;
                }
            }
        }

        // taps 4..8
#pragma unroll 1
        for (int tap = 4; tap < 9; ++tap) {
            int dy = tap / 3, dx = tap - dy * 3;
            const u16* bb_ = WB + ((size_t)(((wv * 4 + icc) * 9 + tap) * 3)) * 2048;
            s16x8 Bh[4], Bm[4], Bl[4];
#pragma unroll
            for (int f = 0; f < 4; ++f) {
                int bu = (f * 16 + cx) * 32 + icl0;
                Bh[f] = *(const s16x8*)&bb_[bu];
                Bm[f] = *(const s16x8*)&bb_[2048 + bu];
                Bl[f] = *(const s16x8*)&bb_[4096 + bu];
            }
#pragma unroll
            for (int pb = 0; pb < 4; ++pb) {
                int pos = (pb + dy) * 18 + cx + dx;
                int au = pos * AROW + (kg << 4);
                s16x8 Ah = *(const s16x8*)&xa[au];
                s16x8 Am = *(const s16x8*)&xa[APLN + au];
                s16x8 Al = *(const s16x8*)&xa[2 * APLN + au];
#pragma unroll
                for (int f = 0; f < 4; ++f) {
                    acc[pb][f] = MFMA16(Ah, Bh[f], acc[pb][f], 0, 0, 0);
                    acc[pb][f] = MFMA16(Ah, Bm[f], acc[pb][f], 0, 0, 0);
                    acc[pb][f] = MFMA16(Am, Bh[f], acc[pb][f], 0, 0, 0);
                    acc[pb][f] = MFMA16(Ah, Bl[f], acc[pb][f], 0, 0, 0);
                    acc[pb][f] = MFMA16(Am, Bm[f], acc[pb][f], 0, 0, 0);
                    acc[pb][f] = MFMA16(Al, Bh[f], acc[pb][f], 0, 0, 0);
                }
            }
        }

        __syncthreads();   // buf[cur^1] writes complete; buf[cur] reads done
    }

    // epilogue: BN + ReLU, channel-last store
#pragma unroll
    for (int f = 0; f < 4; ++f) {
        int oc = wv * 64 + f * 16 + cx;
        float s_ = sa[oc], t_ = ta[oc];
#pragma unroll
        for (int pb = 0; pb < 4; ++pb) {
            int y = y0 + pb;
#pragma unroll
            for (int r = 0; r < 4; ++r) {
                int xc2 = x0 + kg * 4 + r;
                size_t addr = ((size_t)(b * (H_ * W_) + y * W_ + xc2)) * CHID + oc;
                h[addr] = fmaxf(fmaf(acc[pb][f][r], s_, t_), 0.f);
            }
        }
    }
}

// =====================================================================
// K2: conv1x1 as MFMA GEMM (6-term split) + LDS-transpose epilogue
// (round-16 version, frozen).
// =====================================================================
__global__ __launch_bounds__(256) void conv1_kernel(const float* __restrict__ h,
                                                    const u16* __restrict__ WB1,
                                                    const float* __restrict__ tb,
                                                    float* __restrict__ logits,
                                                    float* __restrict__ prob)
{
    __shared__ __align__(16) float hs2[80 * 131];   // 41,920 B
    int t = threadIdx.x;
    int wv = t >> 6;
    int lane = t & 63;
    int cx = lane & 15;
    int kg = lane >> 4;
    int px0 = blockIdx.x * 128 + wv * 32;

    const float* hp0 = h + (size_t)(px0 + cx) * CHID + kg * 8;
    const float* hp1 = hp0 + 16 * CHID;

    f32x4 acc0[5], acc1[5];
#pragma unroll
    for (int f = 0; f < 5; ++f) { acc0[f] = (f32x4)(0.f); acc1[f] = (f32x4)(0.f); }

#pragma unroll 1
    for (int kc = 0; kc < 8; ++kc) {
        s16x8 Ah0, Am0, Al0, Ah1, Am1, Al1;
        {
            float4 a0 = *(const float4*)(hp0 + kc * 32);
            float4 a1 = *(const float4*)(hp0 + kc * 32 + 4);
            float av[8] = {a0.x, a0.y, a0.z, a0.w, a1.x, a1.y, a1.z, a1.w};
#pragma unroll
            for (int j = 0; j < 8; ++j) {
                u16 hh = f2bf(av[j]); float r1 = av[j] - bf2f(hh);
                u16 mm2 = f2bf(r1); float r2 = r1 - bf2f(mm2);
                Ah0[j] = (short)hh; Am0[j] = (short)mm2; Al0[j] = (short)f2bf(r2);
            }
        }
        {
            float4 a0 = *(const float4*)(hp1 + kc * 32);
            float4 a1 = *(const float4*)(hp1 + kc * 32 + 4);
            float av[8] = {a0.x, a0.y, a0.z, a0.w, a1.x, a1.y, a1.z, a1.w};
#pragma unroll
            for (int j = 0; j < 8; ++j) {
                u16 hh = f2bf(av[j]); float r1 = av[j] - bf2f(hh);
                u16 mm2 = f2bf(r1); float r2 = r1 - bf2f(mm2);
                Ah1[j] = (short)hh; Am1[j] = (short)mm2; Al1[j] = (short)f2bf(r2);
            }
        }
#pragma unroll
        for (int f = 0; f < 5; ++f) {
            const u16* bbase = WB1 + ((size_t)(f * 8 + kc) * 3) * 512 + lane * 8;
            s16x8 Bh = *(const s16x8*)bbase;
            s16x8 Bm = *(const s16x8*)(bbase + 512);
            s16x8 Bl = *(const s16x8*)(bbase + 1024);
            acc0[f] = MFMA16(Ah0, Bh, acc0[f], 0, 0, 0);
            acc0[f] = MFMA16(Ah0, Bm, acc0[f], 0, 0, 0);
            acc0[f] = MFMA16(Am0, Bh, acc0[f], 0, 0, 0);
            acc0[f] = MFMA16(Ah0, Bl, acc0[f], 0, 0, 0);
            acc0[f] = MFMA16(Am0, Bm, acc0[f], 0, 0, 0);
            acc0[f] = MFMA16(Al0, Bh, acc0[f], 0, 0, 0);
            acc1[f] = MFMA16(Ah1, Bh, acc1[f], 0, 0, 0);
            acc1[f] = MFMA16(Ah1, Bm, acc1[f], 0, 0, 0);
            acc1[f] = MFMA16(Am1, Bh, acc1[f], 0, 0, 0);
            acc1[f] = MFMA16(Ah1, Bl, acc1[f], 0, 0, 0);
            acc1[f] = MFMA16(Am1, Bm, acc1[f], 0, 0, 0);
            acc1[f] = MFMA16(Al1, Bh, acc1[f], 0, 0, 0);
        }
    }

    // stage to LDS (bias folded): hs2[oc][px_local]
#pragma unroll
    for (int f = 0; f < 5; ++f) {
        int oc = f * 16 + cx;
        float tbv = (oc < COUT) ? tb[oc] : 0.f;
#pragma unroll
        for (int r = 0; r < 4; ++r) {
            int pl = wv * 32 + kg * 4 + r;
            hs2[oc * 131 + pl] = acc0[f][r] + tbv;
            hs2[oc * 131 + pl + 16] = acc1[f][r] + tbv;
        }
    }
    __syncthreads();

    int p0 = blockIdx.x * 128;

    // logits: coalesced px runs per oc
    for (int e = t; e < 65 * 128; e += 256) {
        int px = e & 127;
        int oc = e >> 7;
        int p = p0 + px;
        int b = p / (H_ * W_);
        int yx = p - b * (H_ * W_);
        logits[((size_t)(b * COUT + oc)) * (H_ * W_) + yx] = hs2[oc * 131 + px];
    }

    // prob: per-px 32B float4 pairs (coalesced)
    for (int e = t; e < 8 * 128; e += 256) {
        int px = e & 127;
        int r1 = e >> 7;
        int p = p0 + px;
        int b = p / (H_ * W_);
        int yx = p - b * (H_ * W_);
        int y = yx / W_, xx = yx - y * W_;
        float4 v0, v1;
        v0.x = hs2[(r1 * 8 + 0) * 131 + px];
        v0.y = hs2[(r1 * 8 + 1) * 131 + px];
        v0.z = hs2[(r1 * 8 + 2) * 131 + px];
        v0.w = hs2[(r1 * 8 + 3) * 131 + px];
        v1.x = hs2[(r1 * 8 + 4) * 131 + px];
        v1.y = hs2[(r1 * 8 + 5) * 131 + px];
        v1.z = hs2[(r1 * 8 + 6) * 131 + px];
        v1.w = hs2[(r1 * 8 + 7) * 131 + px];
        float* dst = prob + (size_t)b * (HP * WP) + (y * 8 + r1) * WP + xx * 8;
        *(float4*)dst = v0;
        *(float4*)(dst + 4) = v1;
    }
}

// =====================================================================
// K3: 9x9 local-max keep + candidate compaction (1 global atomic/block)
// =====================================================================
__global__ __launch_bounds__(256) void nms_kernel(const float* __restrict__ prob,
                                                  float* __restrict__ keep_out,
                                                  float* __restrict__ cand,
                                                  int* __restrict__ cnt)
{
    __shared__ float xs[40][40];
    __shared__ float rmax[40][32];
    __shared__ float clist[1024];
    __shared__ int csh;
    __shared__ int gbase;

    int bid = blockIdx.x;
    int tx = bid % 20;
    int ty = (bid / 20) % 15;
    int b = bid / 300;
    const float* pb = prob + (size_t)b * (HP * WP);
    int t = threadIdx.x;

    if (t == 0) csh = 0;

    for (int idx = t; idx < 1600; idx += 256) {
        int c = idx % 40, r = idx / 40;
        int gy = ty * 32 - 4 + r;
        int gx = tx * 32 - 4 + c;
        float v = -INFINITY;
        if (gy >= 0 && gy < HP && gx >= 0 && gx < WP) v = pb[gy * WP + gx];
        xs[r][c] = v;
    }
    __syncthreads();

    for (int idx = t; idx < 1280; idx += 256) {
        int c = idx & 31, r = idx >> 5;
        float m = xs[r][c];
#pragma unroll
        for (int d = 1; d < 9; ++d) m = fmaxf(m, xs[r][c + d]);
        rmax[r][c] = m;
    }
    __syncthreads();

    for (int idx = t; idx < 1024; idx += 256) {
        int c = idx & 31, ro = idx >> 5;
        float m = rmax[ro][c];
#pragma unroll
        for (int d = 1; d < 9; ++d) m = fmaxf(m, rmax[ro + d][c]);
        float v = xs[ro + 4][c + 4];
        float keep = (v == m) ? v : 0.f;
        keep_out[(size_t)b * (HP * WP) + (ty * 32 + ro) * WP + tx * 32 + c] = keep;
        if (keep > 0.f) {
            int i = atomicAdd(&csh, 1);
            clist[i] = keep;
        }
    }
    __syncthreads();

    int m = csh;
    if (m > 0) {
        if (t == 0) gbase = atomicAdd(&cnt[b * 32], m);
        __syncthreads();
        int gb = gbase;
        for (int i = t; i < m; i += 256) {
            int dst = gb + i;
            if (dst < CAND_MAX) cand[b * CAND_MAX + dst] = clist[i];
        }
    }
}

// =====================================================================
// K4: exact kth-largest (k=1000) per batch via 4-pass radix select
// =====================================================================
__global__ __launch_bounds__(256) void select_kernel(const float* __restrict__ cand,
                                                     const int* __restrict__ cnt,
                                                     float* __restrict__ kth)
{
    __shared__ unsigned hist[256];
    __shared__ unsigned sh_prefix, sh_K;

    int b = blockIdx.x;
    int t = threadIdx.x;
    int n = cnt[b * 32];
    if (n > CAND_MAX) n = CAND_MAX;
    if (n < TOPK) {
        if (t == 0) kth[b] = 0.f;
        return;
    }
    if (t == 0) { sh_prefix = 0u; sh_K = TOPK; }
    __syncthreads();
    const float* cb = cand + b * CAND_MAX;

    for (int pass = 3; pass >= 0; --pass) {
        hist[t] = 0u;
        __syncthreads();
        unsigned prefix = sh_prefix;
        unsigned himask = (pass == 3) ? 0u : (0xFFFFFFFFu << ((pass + 1) * 8));
        for (int i = t; i < n; i += 256) {
            unsigned u = __float_as_uint(cb[i]);
            if ((u & himask) == prefix)
                atomicAdd(&hist[(u >> (pass * 8)) & 255], 1u);
        }
        __syncthreads();
        if (t == 0) {
            unsigned K = sh_K, cum = 0;
            int sel = 0;
            for (int v2 = 255; v2 >= 0; --v2) {
                if (cum + hist[v2] >= K) { sel = v2; sh_K = K - cum; break; }
                cum += hist[v2];
            }
            sh_prefix = prefix | ((unsigned)sel << (pass * 8));
        }
        __syncthreads();
    }
    if (t == 0) kth[b] = __uint_as_float(sh_prefix);
}

// =====================================================================
// K5: threshold with kth + binarize
// =====================================================================
__global__ __launch_bounds__(256) void thresh_kernel(const float* __restrict__ keep,
                                                     const float* __restrict__ kth,
                                                     float* __restrict__ prob_nms,
                                                     float* __restrict__ pred)
{
    int i4 = blockIdx.x * 256 + threadIdx.x;
    int b = i4 / (HP * WP / 4);
    float tv = kth[b];
    float4 v = ((const float4*)keep)[i4];
    float4 o;
    o.x = (v.x >= tv) ? v.x : 0.f;
    o.y = (v.y >= tv) ? v.y : 0.f;
    o.z = (v.z >= tv) ? v.z : 0.f;
    o.w = (v.w >= tv) ? v.w : 0.f;
    ((float4*)prob_nms)[i4] = o;
    float4 pr;
    pr.x = (o.x >= DET_THRESH) ? 1.f : 0.f;
    pr.y = (o.y >= DET_THRESH) ? 1.f : 0.f;
    pr.z = (o.z >= DET_THRESH) ? 1.f : 0.f;
    pr.w = (o.w >= DET_THRESH) ? 1.f : 0.f;
    ((float4*)pred)[i4] = pr;
}

// =====================================================================
extern "C" void kernel_launch(void* const* d_in, const int* in_sizes, int n_in,
                              void* d_out, int out_size, void* d_ws, size_t ws_size,
                              hipStream_t stream) {
    const float* x   = (const float*)d_in[0];
    const float* wa  = (const float*)d_in[1];
    const float* ba  = (const float*)d_in[2];
    const float* ga  = (const float*)d_in[3];
    const float* bta = (const float*)d_in[4];
    const float* ma  = (const float*)d_in[5];
    const float* va  = (const float*)d_in[6];
    const float* wb  = (const float*)d_in[7];
    const float* bb  = (const float*)d_in[8];
    const float* gb  = (const float*)d_in[9];
    const float* btb = (const float*)d_in[10];
    const float* mb  = (const float*)d_in[11];
    const float* vb  = (const float*)d_in[12];

    float* out = (float*)d_out;
    float* ws  = (float*)d_ws;

    u16*   WB   = (u16*)ws;
    float* sa   = ws + SA_OFF;
    float* ta   = ws + TA_OFF;
    float* tbv  = ws + TB_OFF;
    u16*   WB1  = (u16*)(ws + WB1_OFF);
    float* h    = ws + H_OFF;
    float* cand = ws + CAND_OFF;
    int*   cnt  = (int*)(ws + CNT_OFF);
    float* kth  = ws + KTH_OFF;

    hipMemsetAsync((void*)cnt, 0, CNT_N * sizeof(int), stream);

    {
        int total = WT_N + 256 + COUT + WB1_U16N;
        prep_kernel<<<(total + 255) / 256, 256, 0, stream>>>(
            wa, ba, ga, bta, ma, va, wb, bb, gb, btb, mb, vb, WB, sa, ta, tbv, WB1);
    }

    conv3_kernel<<<2400, 256, 0, stream>>>(x, WB, sa, ta, h);

    conv1_kernel<<<(B_ * H_ * W_) / 128, 256, 0, stream>>>(
        h, WB1, tbv, out, out + PROB_OFF);

    nms_kernel<<<32 * 15 * 20, 256, 0, stream>>>(
        out + PROB_OFF, out + NMS_OFF, cand, cnt);

    select_kernel<<<B_, 256, 0, stream>>>(cand, cnt, kth);

    thresh_kernel<<<(PROB_N / 4) / 256, 256, 0, stream>>>(
        out + NMS_OFF, kth, out + NMS_OFF, out + PRED_OFF);
}

// Round 18
// 566.094 us; speedup vs baseline: 1.2270x; 1.2270x over previous
//
#include <hip/hip_runtime.h>
#include <math.h>

typedef short s16x8 __attribute__((ext_vector_type(8)));
typedef float f32x4 __attribute__((ext_vector_type(4)));
typedef unsigned short u16;

// ---------------- problem constants ----------------
#define B_    32
#define CIN   128
#define CHID  256
#define H_    60
#define W_    80
#define COUT  65
#define HP    480
#define WP    640
#define TOPK  1000
#define CAND_MAX 8192
#define DET_THRESH 0.015f

// ---------------- output layout (floats) ----------------
#define LOGITS_N (B_*COUT*H_*W_)
#define PROB_N   (B_*HP*WP)
#define PROB_OFF (LOGITS_N)
#define NMS_OFF  (PROB_OFF + PROB_N)
#define PRED_OFF (NMS_OFF + PROB_N)

// ---------------- workspace layout (float offsets) ----------------
#define WB_FN    442368
#define SA_OFF   WB_FN
#define TA_OFF   (SA_OFF + 256)
#define TB_OFF   (TA_OFF + 256)
#define WB1_FN   30720
#define WB1_OFF  (TB_OFF + 128)
#define H_OFF    (WB1_OFF + WB1_FN)
#define H_N      (B_*H_*W_*CHID)
#define CAND_OFF (H_OFF + H_N)
#define CNT_OFF  (CAND_OFF + B_*CAND_MAX)
#define CNT_N    (32*32)
#define KTH_OFF  (CNT_OFF + CNT_N)
#define WT_N     (CHID*CIN*9)
#define WB1_U16N 61440

// conv3 LDS A-layout (round-14): unit (pos,kg) at dword 29*pos + 8*kg.
#define AROW  58
#define APLN  6264

// bf16 helpers (RNE)
__device__ __forceinline__ u16 f2bf(float x) {
    unsigned u = __float_as_uint(x);
    return (u16)((u + 0x7fffu + ((u >> 16) & 1u)) >> 16);
}
__device__ __forceinline__ float bf2f(u16 h) {
    return __uint_as_float(((unsigned)h) << 16);
}

#define MFMA16 __builtin_amdgcn_mfma_f32_16x16x32_bf16

// =====================================================================
// K0: prep — WB (conv3 3-plane split), WB1 (conv1 3-plane split, padded
// to 80 oc, per-fragment layout), sa/ta conv3 BN, tb conv1 BN bias.
// =====================================================================
__global__ void prep_kernel(const float* __restrict__ wa,
                            const float* __restrict__ ba, const float* __restrict__ ga,
                            const float* __restrict__ bta, const float* __restrict__ ma,
                            const float* __restrict__ va,
                            const float* __restrict__ wb, const float* __restrict__ bb,
                            const float* __restrict__ gb, const float* __restrict__ btb,
                            const float* __restrict__ mb, const float* __restrict__ vb,
                            u16* __restrict__ WBo,
                            float* __restrict__ sa, float* __restrict__ ta,
                            float* __restrict__ tb, u16* __restrict__ WB1o)
{
    int gid = blockIdx.x * 256 + threadIdx.x;
    if (gid < WT_N) {
        int icl = gid & 31;
        int ocl = (gid >> 5) & 63;
        int rest = gid >> 11;          // [0,144)
        int tap = rest % 9;
        int cq = rest / 9;             // [0,16)
        int icc = cq & 3, ocq = cq >> 2;
        float v = wa[(((ocq * 64 + ocl) * CIN) + icc * 32 + icl) * 9 + tap];
        u16 hh = f2bf(v); float r1 = v - bf2f(hh);
        u16 mm2 = f2bf(r1); float r2 = r1 - bf2f(mm2);
        u16 ll = f2bf(r2);
        size_t base = ((size_t)(((ocq * 4 + icc) * 9 + tap) * 3)) * 2048
                      + ocl * 32 + icl;
        WBo[base] = hh;
        WBo[base + 2048] = mm2;
        WBo[base + 4096] = ll;
    } else if (gid < WT_N + 256) {
        int oc = gid - WT_N;
        float inv = ga[oc] / sqrtf(va[oc] + 1e-5f);
        sa[oc] = inv;
        ta[oc] = (ba[oc] - ma[oc]) * inv + bta[oc];
    } else if (gid < WT_N + 256 + COUT) {
        int oc = gid - (WT_N + 256);
        float inv = gb[oc] / sqrtf(vb[oc] + 1e-5f);
        tb[oc] = (bb[oc] - mb[oc]) * inv + btb[oc];
    } else if (gid < WT_N + 256 + COUT + WB1_U16N) {
        int idx = gid - (WT_N + 256 + COUT);
        int within = idx & 511;
        int j = within & 7;
        int lane = within >> 3;
        int chunk = idx >> 9;          // [0,120)
        int plane = chunk % 3;
        int kc = (chunk / 3) & 7;
        int ocf = chunk / 24;
        int oc = ocf * 16 + (lane & 15);
        int k = kc * 32 + (lane >> 4) * 8 + j;
        float v = 0.f;
        if (oc < COUT) {
            float inv = gb[oc] / sqrtf(vb[oc] + 1e-5f);
            v = wb[oc * CHID + k] * inv;
        }
        u16 hh = f2bf(v); float r1 = v - bf2f(hh);
        u16 mm2 = f2bf(r1); float r2 = r1 - bf2f(mm2);
        u16 ll = f2bf(r2);
        WB1o[idx] = (plane == 0) ? hh : (plane == 1) ? mm2 : ll;
    }
}

// =====================================================================
// K1: conv3x3 via 6-term split-bf16 MFMA — round-16 structure (best:
// 443 us) + s_setprio(1) around each tap's MFMA cluster (T5: favors
// MFMA waves while the co-resident block stages).
// =====================================================================
__global__ __launch_bounds__(256, 2) void conv3_kernel(const float* __restrict__ x,
                                                       const u16* __restrict__ WB,
                                                       const float* __restrict__ sa,
                                                       const float* __restrict__ ta,
                                                       float* __restrict__ h)
{
    __shared__ __align__(16) u16 xsA[3 * APLN];   // 37584 B

    // bijective XCD swizzle: 2400 blocks = 8 * 300
    int d = blockIdx.x;
    int o = (d & 7) * 300 + (d >> 3);
    int tile = o % 75;
    int b = o / 75;
    int ty = tile / 5, tx = tile % 5;
    int y0 = ty * 4, x0 = tx * 16;

    int t = threadIdx.x;
    int wv = __builtin_amdgcn_readfirstlane(t >> 6);   // 0..3 = ocq
    int lane = t & 63;
    int cx = lane & 15;
    int kg = lane >> 4;
    int icl0 = kg * 8;

    const float* xb = x + (size_t)b * CIN * H_ * W_;

    int goff[14];
#pragma unroll
    for (int j = 0; j < 14; ++j) {
        int e = t + j * 256;
        int go = -1;
        if (e < 3456) {
            int xx = e % 18;
            int yy = (e / 18) % 6;
            int icl = e / 108;
            int gy = y0 + yy - 1, gx = x0 + xx - 1;
            if (gy >= 0 && gy < H_ && gx >= 0 && gx < W_)
                go = icl * (H_ * W_) + gy * W_ + gx;
        }
        goff[j] = go;
    }

    f32x4 acc[4][4];
#pragma unroll
    for (int pb = 0; pb < 4; ++pb)
#pragma unroll
        for (int f = 0; f < 4; ++f) acc[pb][f] = (f32x4)(0.f);

    float xr[14];
#pragma unroll
    for (int j = 0; j < 14; ++j)
        xr[j] = (goff[j] >= 0) ? xb[goff[j]] : 0.f;

#pragma unroll 1
    for (int icc = 0; icc < 4; ++icc) {
        __syncthreads();
#pragma unroll
        for (int j = 0; j < 14; ++j) {
            int e = t + j * 256;
            if (e < 3456) {
                int xx = e % 18;
                int yy = (e / 18) % 6;
                int icl = e / 108;
                float v = xr[j];
                u16 hh = f2bf(v); float r1 = v - bf2f(hh);
                u16 mm2 = f2bf(r1); float r2 = r1 - bf2f(mm2);
                u16 ll = f2bf(r2);
                int pos = yy * 18 + xx;
                int wu = pos * AROW + ((icl >> 3) << 4) + (icl & 7);
                xsA[wu] = hh;
                xsA[APLN + wu] = mm2;
                xsA[2 * APLN + wu] = ll;
            }
        }
        __syncthreads();

        if (icc < 3) {
            const float* xc = xb + (icc + 1) * 32 * (H_ * W_);
#pragma unroll
            for (int j = 0; j < 14; ++j)
                if (goff[j] >= 0) xr[j] = xc[goff[j]];
        }

#pragma unroll 1
        for (int tap = 0; tap < 9; ++tap) {
            int dy = tap / 3, dx = tap - dy * 3;

            const u16* bb_ = WB + ((size_t)(((wv * 4 + icc) * 9 + tap) * 3)) * 2048;
            s16x8 Bh[4], Bm[4], Bl[4];
#pragma unroll
            for (int f = 0; f < 4; ++f) {
                int bu = (f * 16 + cx) * 32 + icl0;
                Bh[f] = *(const s16x8*)&bb_[bu];
                Bm[f] = *(const s16x8*)&bb_[2048 + bu];
                Bl[f] = *(const s16x8*)&bb_[4096 + bu];
            }

            __builtin_amdgcn_s_setprio(1);
#pragma unroll
            for (int pb = 0; pb < 4; ++pb) {
                int pos = (pb + dy) * 18 + cx + dx;
                int au = pos * AROW + (kg << 4);
                s16x8 Ah = *(const s16x8*)&xsA[au];
                s16x8 Am = *(const s16x8*)&xsA[APLN + au];
                s16x8 Al = *(const s16x8*)&xsA[2 * APLN + au];
#pragma unroll
                for (int f = 0; f < 4; ++f) {
                    acc[pb][f] = MFMA16(Ah, Bh[f], acc[pb][f], 0, 0, 0);
                    acc[pb][f] = MFMA16(Ah, Bm[f], acc[pb][f], 0, 0, 0);
                    acc[pb][f] = MFMA16(Am, Bh[f], acc[pb][f], 0, 0, 0);
                    acc[pb][f] = MFMA16(Ah, Bl[f], acc[pb][f], 0, 0, 0);
                    acc[pb][f] = MFMA16(Am, Bm[f], acc[pb][f], 0, 0, 0);
                    acc[pb][f] = MFMA16(Al, Bh[f], acc[pb][f], 0, 0, 0);
                }
            }
            __builtin_amdgcn_s_setprio(0);
        }
    }

    // epilogue: BN + ReLU, channel-last store
#pragma unroll
    for (int f = 0; f < 4; ++f) {
        int oc = wv * 64 + f * 16 + cx;
        float s_ = sa[oc], t_ = ta[oc];
#pragma unroll
        for (int pb = 0; pb < 4; ++pb) {
            int y = y0 + pb;
#pragma unroll
            for (int r = 0; r < 4; ++r) {
                int xc2 = x0 + kg * 4 + r;
                size_t addr = ((size_t)(b * (H_ * W_) + y * W_ + xc2)) * CHID + oc;
                h[addr] = fmaxf(fmaf(acc[pb][f][r], s_, t_), 0.f);
            }
        }
    }
}

// =====================================================================
// K2: conv1x1 as MFMA GEMM (6-term split) + LDS-transpose epilogue
// (round-16 version, frozen).
// =====================================================================
__global__ __launch_bounds__(256) void conv1_kernel(const float* __restrict__ h,
                                                    const u16* __restrict__ WB1,
                                                    const float* __restrict__ tb,
                                                    float* __restrict__ logits,
                                                    float* __restrict__ prob)
{
    __shared__ __align__(16) float hs2[80 * 131];   // 41,920 B
    int t = threadIdx.x;
    int wv = t >> 6;
    int lane = t & 63;
    int cx = lane & 15;
    int kg = lane >> 4;
    int px0 = blockIdx.x * 128 + wv * 32;

    const float* hp0 = h + (size_t)(px0 + cx) * CHID + kg * 8;
    const float* hp1 = hp0 + 16 * CHID;

    f32x4 acc0[5], acc1[5];
#pragma unroll
    for (int f = 0; f < 5; ++f) { acc0[f] = (f32x4)(0.f); acc1[f] = (f32x4)(0.f); }

#pragma unroll 1
    for (int kc = 0; kc < 8; ++kc) {
        s16x8 Ah0, Am0, Al0, Ah1, Am1, Al1;
        {
            float4 a0 = *(const float4*)(hp0 + kc * 32);
            float4 a1 = *(const float4*)(hp0 + kc * 32 + 4);
            float av[8] = {a0.x, a0.y, a0.z, a0.w, a1.x, a1.y, a1.z, a1.w};
#pragma unroll
            for (int j = 0; j < 8; ++j) {
                u16 hh = f2bf(av[j]); float r1 = av[j] - bf2f(hh);
                u16 mm2 = f2bf(r1); float r2 = r1 - bf2f(mm2);
                Ah0[j] = (short)hh; Am0[j] = (short)mm2; Al0[j] = (short)f2bf(r2);
            }
        }
        {
            float4 a0 = *(const float4*)(hp1 + kc * 32);
            float4 a1 = *(const float4*)(hp1 + kc * 32 + 4);
            float av[8] = {a0.x, a0.y, a0.z, a0.w, a1.x, a1.y, a1.z, a1.w};
#pragma unroll
            for (int j = 0; j < 8; ++j) {
                u16 hh = f2bf(av[j]); float r1 = av[j] - bf2f(hh);
                u16 mm2 = f2bf(r1); float r2 = r1 - bf2f(mm2);
                Ah1[j] = (short)hh; Am1[j] = (short)mm2; Al1[j] = (short)f2bf(r2);
            }
        }
#pragma unroll
        for (int f = 0; f < 5; ++f) {
            const u16* bbase = WB1 + ((size_t)(f * 8 + kc) * 3) * 512 + lane * 8;
            s16x8 Bh = *(const s16x8*)bbase;
            s16x8 Bm = *(const s16x8*)(bbase + 512);
            s16x8 Bl = *(const s16x8*)(bbase + 1024);
            acc0[f] = MFMA16(Ah0, Bh, acc0[f], 0, 0, 0);
            acc0[f] = MFMA16(Ah0, Bm, acc0[f], 0, 0, 0);
            acc0[f] = MFMA16(Am0, Bh, acc0[f], 0, 0, 0);
            acc0[f] = MFMA16(Ah0, Bl, acc0[f], 0, 0, 0);
            acc0[f] = MFMA16(Am0, Bm, acc0[f], 0, 0, 0);
            acc0[f] = MFMA16(Al0, Bh, acc0[f], 0, 0, 0);
            acc1[f] = MFMA16(Ah1, Bh, acc1[f], 0, 0, 0);
            acc1[f] = MFMA16(Ah1, Bm, acc1[f], 0, 0, 0);
            acc1[f] = MFMA16(Am1, Bh, acc1[f], 0, 0, 0);
            acc1[f] = MFMA16(Ah1, Bl, acc1[f], 0, 0, 0);
            acc1[f] = MFMA16(Am1, Bm, acc1[f], 0, 0, 0);
            acc1[f] = MFMA16(Al1, Bh, acc1[f], 0, 0, 0);
        }
    }

    // stage to LDS (bias folded): hs2[oc][px_local]
#pragma unroll
    for (int f = 0; f < 5; ++f) {
        int oc = f * 16 + cx;
        float tbv = (oc < COUT) ? tb[oc] : 0.f;
#pragma unroll
        for (int r = 0; r < 4; ++r) {
            int pl = wv * 32 + kg * 4 + r;
            hs2[oc * 131 + pl] = acc0[f][r] + tbv;
            hs2[oc * 131 + pl + 16] = acc1[f][r] + tbv;
        }
    }
    __syncthreads();

    int p0 = blockIdx.x * 128;

    // logits: coalesced px runs per oc
    for (int e = t; e < 65 * 128; e += 256) {
        int px = e & 127;
        int oc = e >> 7;
        int p = p0 + px;
        int b = p / (H_ * W_);
        int yx = p - b * (H_ * W_);
        logits[((size_t)(b * COUT + oc)) * (H_ * W_) + yx] = hs2[oc * 131 + px];
    }

    // prob: per-px 32B float4 pairs (coalesced)
    for (int e = t; e < 8 * 128; e += 256) {
        int px = e & 127;
        int r1 = e >> 7;
        int p = p0 + px;
        int b = p / (H_ * W_);
        int yx = p - b * (H_ * W_);
        int y = yx / W_, xx = yx - y * W_;
        float4 v0, v1;
        v0.x = hs2[(r1 * 8 + 0) * 131 + px];
        v0.y = hs2[(r1 * 8 + 1) * 131 + px];
        v0.z = hs2[(r1 * 8 + 2) * 131 + px];
        v0.w = hs2[(r1 * 8 + 3) * 131 + px];
        v1.x = hs2[(r1 * 8 + 4) * 131 + px];
        v1.y = hs2[(r1 * 8 + 5) * 131 + px];
        v1.z = hs2[(r1 * 8 + 6) * 131 + px];
        v1.w = hs2[(r1 * 8 + 7) * 131 + px];
        float* dst = prob + (size_t)b * (HP * WP) + (y * 8 + r1) * WP + xx * 8;
        *(float4*)dst = v0;
        *(float4*)(dst + 4) = v1;
    }
}

// =====================================================================
// K3: 9x9 local-max keep + candidate compaction (1 global atomic/block)
// =====================================================================
__global__ __launch_bounds__(256) void nms_kernel(const float* __restrict__ prob,
                                                  float* __restrict__ keep_out,
                                                  float* __restrict__ cand,
                                                  int* __restrict__ cnt)
{
    __shared__ float xs[40][40];
    __shared__ float rmax[40][32];
    __shared__ float clist[1024];
    __shared__ int csh;
    __shared__ int gbase;

    int bid = blockIdx.x;
    int tx = bid % 20;
    int ty = (bid / 20) % 15;
    int b = bid / 300;
    const float* pb = prob + (size_t)b * (HP * WP);
    int t = threadIdx.x;

    if (t == 0) csh = 0;

    for (int idx = t; idx < 1600; idx += 256) {
        int c = idx % 40, r = idx / 40;
        int gy = ty * 32 - 4 + r;
        int gx = tx * 32 - 4 + c;
        float v = -INFINITY;
        if (gy >= 0 && gy < HP && gx >= 0 && gx < WP) v = pb[gy * WP + gx];
        xs[r][c] = v;
    }
    __syncthreads();

    for (int idx = t; idx < 1280; idx += 256) {
        int c = idx & 31, r = idx >> 5;
        float m = xs[r][c];
#pragma unroll
        for (int d = 1; d < 9; ++d) m = fmaxf(m, xs[r][c + d]);
        rmax[r][c] = m;
    }
    __syncthreads();

    for (int idx = t; idx < 1024; idx += 256) {
        int c = idx & 31, ro = idx >> 5;
        float m = rmax[ro][c];
#pragma unroll
        for (int d = 1; d < 9; ++d) m = fmaxf(m, rmax[ro + d][c]);
        float v = xs[ro + 4][c + 4];
        float keep = (v == m) ? v : 0.f;
        keep_out[(size_t)b * (HP * WP) + (ty * 32 + ro) * WP + tx * 32 + c] = keep;
        if (keep > 0.f) {
            int i = atomicAdd(&csh, 1);
            clist[i] = keep;
        }
    }
    __syncthreads();

    int m = csh;
    if (m > 0) {
        if (t == 0) gbase = atomicAdd(&cnt[b * 32], m);
        __syncthreads();
        int gb = gbase;
        for (int i = t; i < m; i += 256) {
            int dst = gb + i;
            if (dst < CAND_MAX) cand[b * CAND_MAX + dst] = clist[i];
        }
    }
}

// =====================================================================
// K4: exact kth-largest (k=1000) per batch via 4-pass radix select
// =====================================================================
__global__ __launch_bounds__(256) void select_kernel(const float* __restrict__ cand,
                                                     const int* __restrict__ cnt,
                                                     float* __restrict__ kth)
{
    __shared__ unsigned hist[256];
    __shared__ unsigned sh_prefix, sh_K;

    int b = blockIdx.x;
    int t = threadIdx.x;
    int n = cnt[b * 32];
    if (n > CAND_MAX) n = CAND_MAX;
    if (n < TOPK) {
        if (t == 0) kth[b] = 0.f;
        return;
    }
    if (t == 0) { sh_prefix = 0u; sh_K = TOPK; }
    __syncthreads();
    const float* cb = cand + b * CAND_MAX;

    for (int pass = 3; pass >= 0; --pass) {
        hist[t] = 0u;
        __syncthreads();
        unsigned prefix = sh_prefix;
        unsigned himask = (pass == 3) ? 0u : (0xFFFFFFFFu << ((pass + 1) * 8));
        for (int i = t; i < n; i += 256) {
            unsigned u = __float_as_uint(cb[i]);
            if ((u & himask) == prefix)
                atomicAdd(&hist[(u >> (pass * 8)) & 255], 1u);
        }
        __syncthreads();
        if (t == 0) {
            unsigned K = sh_K, cum = 0;
            int sel = 0;
            for (int v2 = 255; v2 >= 0; --v2) {
                if (cum + hist[v2] >= K) { sel = v2; sh_K = K - cum; break; }
                cum += hist[v2];
            }
            sh_prefix = prefix | ((unsigned)sel << (pass * 8));
        }
        __syncthreads();
    }
    if (t == 0) kth[b] = __uint_as_float(sh_prefix);
}

// =====================================================================
// K5: threshold with kth + binarize
// =====================================================================
__global__ __launch_bounds__(256) void thresh_kernel(const float* __restrict__ keep,
                                                     const float* __restrict__ kth,
                                                     float* __restrict__ prob_nms,
                                                     float* __restrict__ pred)
{
    int i4 = blockIdx.x * 256 + threadIdx.x;
    int b = i4 / (HP * WP / 4);
    float tv = kth[b];
    float4 v = ((const float4*)keep)[i4];
    float4 o;
    o.x = (v.x >= tv) ? v.x : 0.f;
    o.y = (v.y >= tv) ? v.y : 0.f;
    o.z = (v.z >= tv) ? v.z : 0.f;
    o.w = (v.w >= tv) ? v.w : 0.f;
    ((float4*)prob_nms)[i4] = o;
    float4 pr;
    pr.x = (o.x >= DET_THRESH) ? 1.f : 0.f;
    pr.y = (o.y >= DET_THRESH) ? 1.f : 0.f;
    pr.z = (o.z >= DET_THRESH) ? 1.f : 0.f;
    pr.w = (o.w >= DET_THRESH) ? 1.f : 0.f;
    ((float4*)pred)[i4] = pr;
}

// =====================================================================
extern "C" void kernel_launch(void* const* d_in, const int* in_sizes, int n_in,
                              void* d_out, int out_size, void* d_ws, size_t ws_size,
                              hipStream_t stream) {
    const float* x   = (const float*)d_in[0];
    const float* wa  = (const float*)d_in[1];
    const float* ba  = (const float*)d_in[2];
    const float* ga  = (const float*)d_in[3];
    const float* bta = (const float*)d_in[4];
    const float* ma  = (const float*)d_in[5];
    const float* va  = (const float*)d_in[6];
    const float* wb  = (const float*)d_in[7];
    const float* bb  = (const float*)d_in[8];
    const float* gb  = (const float*)d_in[9];
    const float* btb = (const float*)d_in[10];
    const float* mb  = (const float*)d_in[11];
    const float* vb  = (const float*)d_in[12];

    float* out = (float*)d_out;
    float* ws  = (float*)d_ws;

    u16*   WB   = (u16*)ws;
    float* sa   = ws + SA_OFF;
    float* ta   = ws + TA_OFF;
    float* tbv  = ws + TB_OFF;
    u16*   WB1  = (u16*)(ws + WB1_OFF);
    float* h    = ws + H_OFF;
    float* cand = ws + CAND_OFF;
    int*   cnt  = (int*)(ws + CNT_OFF);
    float* kth  = ws + KTH_OFF;

    hipMemsetAsync((void*)cnt, 0, CNT_N * sizeof(int), stream);

    {
        int total = WT_N + 256 + COUT + WB1_U16N;
        prep_kernel<<<(total + 255) / 256, 256, 0, stream>>>(
            wa, ba, ga, bta, ma, va, wb, bb, gb, btb, mb, vb, WB, sa, ta, tbv, WB1);
    }

    conv3_kernel<<<2400, 256, 0, stream>>>(x, WB, sa, ta, h);

    conv1_kernel<<<(B_ * H_ * W_) / 128, 256, 0, stream>>>(
        h, WB1, tbv, out, out + PROB_OFF);

    nms_kernel<<<32 * 15 * 20, 256, 0, stream>>>(
        out + PROB_OFF, out + NMS_OFF, cand, cnt);

    select_kernel<<<B_, 256, 0, stream>>>(cand, cnt, kth);

    thresh_kernel<<<(PROB_N / 4) / 256, 256, 0, stream>>>(
        out + NMS_OFF, kth, out + NMS_OFF, out + PRED_OFF);
}